// Round 19
// baseline (417.482 us; speedup 1.0000x reference)
//
#include <hip/hip_runtime.h>

typedef unsigned short u16;
typedef __attribute__((ext_vector_type(8))) short bf16x8;
typedef __attribute__((ext_vector_type(4))) float fx4;

#define MFMA16(a, b, c) __builtin_amdgcn_mfma_f32_16x16x32_bf16((a), (b), (c), 0, 0, 0)

__device__ __forceinline__ u16 f2bf(float f) {
  unsigned u = __float_as_uint(f);
  u += 0x7fffu + ((u >> 16) & 1u);
  return (u16)(u >> 16);
}

__device__ __forceinline__ void gload_lds16(const void* g, void* l) {
  __builtin_amdgcn_global_load_lds((const __attribute__((address_space(1))) void*)g,
                                   (__attribute__((address_space(3))) void*)l,
                                   16, 0, 0);
}

// ---------------- fused weight prep: 6 transposes (fp32 -> bf16, W^T) ----------------
struct WP {
  const float* s[6];
  u16* d[6];
};
__global__ __launch_bounds__(256) void tcvt_all(WP p) {
  __shared__ float t[32][33];
  const int id = blockIdx.x;
  int which, bx, by, R, C;
  if (id < 4096) {        // Wq,Wk,Wv,Wo: 1024x1024
    which = id >> 10;
    const int q = id & 1023;
    bx = q >> 5; by = q & 31; R = 1024; C = 1024;
  } else if (id < 8192) { // W1: 1024x4096 -> dst 4096x1024
    which = 4;
    const int q = id - 4096;
    bx = q & 127; by = q >> 7; R = 1024; C = 4096;
  } else {                // W2: 4096x1024 -> dst 1024x4096
    which = 5;
    const int q = id - 8192;
    bx = q & 31; by = q >> 5; R = 4096; C = 1024;
  }
  const float* src = p.s[which];
  u16* dst = p.d[which];
  const int tx = threadIdx.x & 31, ty = threadIdx.x >> 5;  // 32x8
#pragma unroll
  for (int i = 0; i < 4; ++i)
    t[ty + i * 8][tx] = src[(size_t)(by * 32 + ty + i * 8) * C + bx * 32 + tx];
  __syncthreads();
#pragma unroll
  for (int i = 0; i < 4; ++i)
    dst[(size_t)(bx * 32 + ty + i * 8) * R + by * 32 + tx] = f2bf(t[tx][ty + i * 8]);
}

// ---------------- layernorm: fp32 [rows][1024] -> bf16 ----------------
__global__ __launch_bounds__(256) void ln_kernel(const float* __restrict__ x,
                                                 const float* __restrict__ sc,
                                                 const float* __restrict__ sh,
                                                 u16* __restrict__ out) {
  const int row = blockIdx.x, tid = threadIdx.x;
  const float4 v = ((const float4*)(x + (size_t)row * 1024))[tid];
  float s = v.x + v.y + v.z + v.w;
  float ss = v.x * v.x + v.y * v.y + v.z * v.z + v.w * v.w;
#pragma unroll
  for (int d = 32; d >= 1; d >>= 1) {
    s += __shfl_xor(s, d);
    ss += __shfl_xor(ss, d);
  }
  __shared__ float rs[4], rq[4];
  const int w = tid >> 6;
  if ((tid & 63) == 0) { rs[w] = s; rq[w] = ss; }
  __syncthreads();
  s = rs[0] + rs[1] + rs[2] + rs[3];
  ss = rq[0] + rq[1] + rq[2] + rq[3];
  const float mean = s * (1.f / 1024.f);
  const float var = ss * (1.f / 1024.f) - mean * mean;
  const float rstd = rsqrtf(var + 1e-5f);
  const float4 g = ((const float4*)sc)[tid];
  const float4 b = ((const float4*)sh)[tid];
  ushort4 o;
  o.x = f2bf(g.x * (v.x - mean) * rstd + b.x);
  o.y = f2bf(g.y * (v.y - mean) * rstd + b.y);
  o.z = f2bf(g.z * (v.z - mean) * rstd + b.z);
  o.w = f2bf(g.w * (v.w - mean) * rstd + b.w);
  ((ushort4*)(out + (size_t)row * 1024))[tid] = o;
}

// XCD-aware tile mapping (NTM multiple of 8): bid%8=xcd; tM=xcd+8*(i/NTN); tN=i%NTN.
__device__ __forceinline__ void xcd_map(int bid, int NTN, int& tMi, int& tNi) {
  const int xcd = bid & 7, i = bid >> 3;
  tMi = xcd + 8 * (i / NTN);
  tNi = i % NTN;
}

// Inlined, fully-unrolled epilogue (rule #20: NO address-taken acc, NO runtime idx).
#define EPILOGUE(MODE, MRv)                                                        \
  _Pragma("unroll") for (int m = 0; m < (MRv); ++m) {                              \
    const int rgb = tM + wm * ((MRv) * 16) + m * 16 + hi * 4;                      \
    _Pragma("unroll") for (int n = 0; n < 4; ++n) {                                \
      const int cg = tN + wn * 64 + n * 16 + lo;                                   \
      _Pragma("unroll") for (int r = 0; r < 4; ++r) {                              \
        const float v = acc[m][n][r];                                              \
        const int rg = rgb + r;                                                    \
        if constexpr ((MODE) == 0) {                                               \
          const int which = cg >> 10, c = cg & 1023;                               \
          const int head = c >> 6, dhi = c & 63;                                   \
          const int b = rg >> 11, sidx = rg & 2047;                                \
          const int bh = b * 16 + head;                                            \
          const u16 bv = f2bf(v);                                                  \
          if (which == 0)      qd[((size_t)bh * 2048 + sidx) * 64 + dhi] = bv;     \
          else if (which == 1) kd[((size_t)bh * 2048 + sidx) * 64 + dhi] = bv;     \
          else                 vd[((size_t)bh * 64 + dhi) * 2048 + sidx] = bv;     \
        } else if constexpr ((MODE) == 1) {                                        \
          float* o = (float*)outp;                                                 \
          const size_t idx = (size_t)rg * 1024 + cg;                               \
          o[idx] = aux[idx] + v;                                                   \
        } else if constexpr ((MODE) == 2) {                                        \
          const float xx = v + aux[cg];                                            \
          const float t2 = xx + 0.044715f * xx * xx * xx;                          \
          const float e = __expf(1.5957691216057308f * t2);                        \
          const float th = 1.f - 2.f / (e + 1.f);                                  \
          ((u16*)outp)[(size_t)rg * 4096 + cg] = f2bf(0.5f * xx * (1.f + th));     \
        } else {                                                                   \
          float* o = (float*)outp;                                                 \
          const size_t idx = (size_t)rg * 1024 + cg;                               \
          o[idx] = o[idx] + v + aux[cg];                                           \
        }                                                                          \
      }                                                                            \
    }                                                                              \
  }

// ---------------- 4-phase pipelined bf16 GEMM (256x128, BK=64, 512 thr) --------------
// Register-fragment ping-pong: phase p's frags prefetched during phase p-1 (reads in
// flight across p-1's MFMA; drained at p's lgkmcnt(0)). vmcnt(6)/phase guarantees half
// h+1 resident at phase h (newest-6 = halves h+2,h+3). WAR barrier-separated.
template <int MODE>
__global__ __launch_bounds__(512, 1) void gemm4p(
    const u16* __restrict__ A, const u16* __restrict__ Bt, int K, int NTN,
    void* __restrict__ outp, const float* __restrict__ aux,
    u16* __restrict__ qd, u16* __restrict__ kd, u16* __restrict__ vd) {
  __shared__ u16 lA[2][2][256 * 32];
  __shared__ u16 lB[2][2][128 * 32];
  const int tid = threadIdx.x;
  const int lane = tid & 63, w = tid >> 6;
  const int lo = lane & 15, hi = lane >> 4;
  const int wm = w >> 1, wn = w & 1;
  int tMi, tNi;
  xcd_map(blockIdx.x, NTN, tMi, tNi);
  const int tM = tMi * 256, tN = tNi * 128;
  const int NT = K >> 6;
  const int NIT = K >> 7;

#define STG4(TI, H, GK)                                                           \
  do {                                                                            \
    _Pragma("unroll") for (int j = 0; j < 2; ++j) {                               \
      const int idx = j * 512 + tid;                                              \
      const int row = idx >> 2, u = idx & 3;                                      \
      gload_lds16(A + (size_t)(tM + row) * K + (GK) + ((u ^ ((row >> 1) & 3)) * 8), \
                  &lA[TI][H][idx * 8]);                                           \
    }                                                                             \
    {                                                                             \
      const int row = tid >> 2, u = tid & 3;                                      \
      gload_lds16(Bt + (size_t)(tN + row) * K + (GK) + ((u ^ ((row >> 1) & 3)) * 8), \
                  &lB[TI][H][tid * 8]);                                           \
    }                                                                             \
  } while (0)

#define LDFRAG4(AF, BF, TI, H)                                                    \
  do {                                                                            \
    _Pragma("unroll") for (int mi = 0; mi < 4; ++mi) {                            \
      const int R = wm * 64 + mi * 16 + lo;                                       \
      AF[mi] = *(const bf16x8*)&lA[TI][H][R * 32 + ((hi ^ ((R >> 1) & 3)) * 8)];  \
    }                                                                             \
    _Pragma("unroll") for (int n = 0; n < 4; ++n) {                               \
      const int R = wn * 64 + n * 16 + lo;                                        \
      BF[n] = *(const bf16x8*)&lB[TI][H][R * 32 + ((hi ^ ((R >> 1) & 3)) * 8)];   \
    }                                                                             \
  } while (0)

#define PHASE4(CA, CB, PREF_STMT, STAGE_STMT, VMSTR)                              \
  {                                                                               \
    STAGE_STMT;                                                                   \
    asm volatile("s_waitcnt " VMSTR ::: "memory");                                \
    __builtin_amdgcn_s_barrier();                                                 \
    asm volatile("s_waitcnt lgkmcnt(0)" ::: "memory");                            \
    __builtin_amdgcn_sched_barrier(0);                                            \
    PREF_STMT;                                                                    \
    __builtin_amdgcn_s_setprio(1);                                                \
    _Pragma("unroll") for (int mi = 0; mi < 4; ++mi)                              \
      _Pragma("unroll") for (int n = 0; n < 4; ++n)                               \
        acc[mi][n] = MFMA16(CA[mi], CB[n], acc[mi][n]);                           \
    __builtin_amdgcn_s_setprio(0);                                                \
    __builtin_amdgcn_sched_barrier(0);                                            \
    __builtin_amdgcn_s_barrier();                                                 \
    __builtin_amdgcn_sched_barrier(0);                                            \
  }

  fx4 acc[4][4];
#pragma unroll
  for (int m = 0; m < 4; ++m)
#pragma unroll
    for (int n = 0; n < 4; ++n) acc[m][n] = (fx4){0.f, 0.f, 0.f, 0.f};
  bf16x8 afrA[4], bfrA[4], afrB[4], bfrB[4];

  // prologue: halves 0,1,2; wait half0 landed; preload phase-0 frags.
  STG4(0, 0, 0);
  STG4(0, 1, 32);
  STG4(1, 0, 64);
  asm volatile("s_waitcnt vmcnt(6)" ::: "memory");
  __builtin_amdgcn_s_barrier();
  __builtin_amdgcn_sched_barrier(0);
  LDFRAG4(afrA, bfrA, 0, 0);

  for (int it = 0; it < NIT - 1; ++it) {
    const int t0 = 2 * it;
    PHASE4(afrA, bfrA, LDFRAG4(afrB, bfrB, 0, 1), STG4(1, 1, (t0 + 1) * 64 + 32), "vmcnt(6)")
    PHASE4(afrB, bfrB, LDFRAG4(afrA, bfrA, 1, 0), STG4(0, 0, (t0 + 2) * 64), "vmcnt(6)")
    PHASE4(afrA, bfrA, LDFRAG4(afrB, bfrB, 1, 1), STG4(0, 1, (t0 + 2) * 64 + 32), "vmcnt(6)")
    PHASE4(afrB, bfrB, LDFRAG4(afrA, bfrA, 0, 0), STG4(1, 0, (t0 + 3) * 64), "vmcnt(6)")
  }
  {  // final iteration: t0 = NT-2; tail vmcnts actually await last halves
    const int t0 = NT - 2;
    PHASE4(afrA, bfrA, LDFRAG4(afrB, bfrB, 0, 1), STG4(1, 1, (t0 + 1) * 64 + 32), "vmcnt(6)")
    PHASE4(afrB, bfrB, LDFRAG4(afrA, bfrA, 1, 0), ((void)0), "vmcnt(3)")
    PHASE4(afrA, bfrA, LDFRAG4(afrB, bfrB, 1, 1), ((void)0), "vmcnt(0)")
    PHASE4(afrB, bfrB, ((void)0), ((void)0), "vmcnt(0)")
  }
#undef PHASE4
#undef LDFRAG4
#undef STG4

  EPILOGUE(MODE, 4)
}

// ---------------- 8-phase pipelined bf16 GEMM (256x256, BK=64) — MLP1 ----------------
// Same fragment ping-pong; B-frags persist 2 phases, prefetched with the mh0 A-frags.
template <int MODE>
__global__ __launch_bounds__(512, 1) void gemm8p(
    const u16* __restrict__ A, const u16* __restrict__ Bt, int K, int NTN,
    void* __restrict__ outp, const float* __restrict__ aux,
    u16* __restrict__ qd, u16* __restrict__ kd, u16* __restrict__ vd) {
  __shared__ u16 lA[2][2][256 * 32];
  __shared__ u16 lB[2][2][256 * 32];
  const int tid = threadIdx.x;
  const int lane = tid & 63, w = tid >> 6;
  const int lo = lane & 15, hi = lane >> 4;
  const int wm = w >> 2, wn = w & 3;
  int tMi, tNi;
  xcd_map(blockIdx.x, NTN, tMi, tNi);
  const int tM = tMi * 256, tN = tNi * 256;
  const int NIT = K >> 7;

#define STG_A(TI, KSH, GK)                                                        \
  do {                                                                            \
    _Pragma("unroll") for (int j = 0; j < 2; ++j) {                               \
      const int idx = j * 512 + tid;                                              \
      const int row = idx >> 2, u = idx & 3;                                      \
      gload_lds16(A + (size_t)(tM + row) * K + (GK) + ((u ^ ((row >> 1) & 3)) * 8), \
                  &lA[TI][KSH][idx * 8]);                                         \
    }                                                                             \
  } while (0)
#define STG_B(TI, KSH, GK)                                                        \
  do {                                                                            \
    _Pragma("unroll") for (int j = 0; j < 2; ++j) {                               \
      const int idx = j * 512 + tid;                                              \
      const int row = idx >> 2, u = idx & 3;                                      \
      gload_lds16(Bt + (size_t)(tN + row) * K + (GK) + ((u ^ ((row >> 1) & 3)) * 8), \
                  &lB[TI][KSH][idx * 8]);                                         \
    }                                                                             \
  } while (0)

#define LDA8(AF, TI, KSH, MH)                                                     \
  do {                                                                            \
    _Pragma("unroll") for (int mi = 0; mi < 4; ++mi) {                            \
      const int R = wm * 128 + ((MH) * 4 + mi) * 16 + lo;                         \
      AF[mi] = *(const bf16x8*)&lA[TI][KSH][R * 32 + ((hi ^ ((R >> 1) & 3)) * 8)]; \
    }                                                                             \
  } while (0)
#define LDB8(BF, TI, KSH)                                                         \
  do {                                                                            \
    _Pragma("unroll") for (int n = 0; n < 4; ++n) {                               \
      const int R = wn * 64 + n * 16 + lo;                                        \
      BF[n] = *(const bf16x8*)&lB[TI][KSH][R * 32 + ((hi ^ ((R >> 1) & 3)) * 8)]; \
    }                                                                             \
  } while (0)

#define PHASE8(MH, CA, CB, PREF_STMT, STAGE_STMT, VMSTR)                          \
  {                                                                               \
    STAGE_STMT;                                                                   \
    asm volatile("s_waitcnt " VMSTR ::: "memory");                                \
    __builtin_amdgcn_s_barrier();                                                 \
    asm volatile("s_waitcnt lgkmcnt(0)" ::: "memory");                            \
    __builtin_amdgcn_sched_barrier(0);                                            \
    PREF_STMT;                                                                    \
    __builtin_amdgcn_s_setprio(1);                                                \
    _Pragma("unroll") for (int mi = 0; mi < 4; ++mi)                              \
      _Pragma("unroll") for (int n = 0; n < 4; ++n)                               \
        acc[(MH) * 4 + mi][n] = MFMA16(CA[mi], CB[n], acc[(MH) * 4 + mi][n]);     \
    __builtin_amdgcn_s_setprio(0);                                                \
    __builtin_amdgcn_sched_barrier(0);                                            \
    __builtin_amdgcn_s_barrier();                                                 \
    __builtin_amdgcn_sched_barrier(0);                                            \
  }

  fx4 acc[8][4];
#pragma unroll
  for (int m = 0; m < 8; ++m)
#pragma unroll
    for (int n = 0; n < 4; ++n) acc[m][n] = (fx4){0.f, 0.f, 0.f, 0.f};
  bf16x8 afrA[4], afrB[4], bfrA[4], bfrB[4];

  STG_A(0, 0, 0);
  STG_B(0, 0, 0);
  STG_A(0, 1, 32);
  STG_B(0, 1, 32);
  STG_A(1, 0, 64);
  STG_B(1, 0, 64);
  asm volatile("s_waitcnt vmcnt(4)" ::: "memory");
  __builtin_amdgcn_s_barrier();
  __builtin_amdgcn_sched_barrier(0);
  LDA8(afrA, 0, 0, 0);
  LDB8(bfrA, 0, 0);

  for (int it = 0; it < NIT - 1; ++it) {
    const int t0 = 2 * it;
    PHASE8(0, afrA, bfrA, LDA8(afrB, 0, 0, 1), STG_A(1, 1, (t0 + 1) * 64 + 32), "vmcnt(4)")
    PHASE8(1, afrB, bfrA, { LDA8(afrA, 0, 1, 0); LDB8(bfrB, 0, 1); }, STG_B(1, 1, (t0 + 1) * 64 + 32), "vmcnt(4)")
    PHASE8(0, afrA, bfrB, LDA8(afrB, 0, 1, 1), STG_A(0, 0, (t0 + 2) * 64), "vmcnt(4)")
    PHASE8(1, afrB, bfrB, { LDA8(afrA, 1, 0, 0); LDB8(bfrA, 1, 0); }, STG_B(0, 0, (t0 + 2) * 64), "vmcnt(4)")
    PHASE8(0, afrA, bfrA, LDA8(afrB, 1, 0, 1), STG_A(0, 1, (t0 + 2) * 64 + 32), "vmcnt(4)")
    PHASE8(1, afrB, bfrA, { LDA8(afrA, 1, 1, 0); LDB8(bfrB, 1, 1); }, STG_B(0, 1, (t0 + 2) * 64 + 32), "vmcnt(4)")
    PHASE8(0, afrA, bfrB, LDA8(afrB, 1, 1, 1), STG_A(1, 0, (t0 + 3) * 64), "vmcnt(4)")
    PHASE8(1, afrB, bfrB, { LDA8(afrA, 0, 0, 0); LDB8(bfrA, 0, 0); }, STG_B(1, 0, (t0 + 3) * 64), "vmcnt(4)")
  }
  {  // final iteration: t0 = NIT*2-2; only tile t0+1 h1 still to stage
    const int t0 = 2 * (NIT - 1);
    PHASE8(0, afrA, bfrA, LDA8(afrB, 0, 0, 1), STG_A(1, 1, (t0 + 1) * 64 + 32), "vmcnt(4)")
    PHASE8(1, afrB, bfrA, { LDA8(afrA, 0, 1, 0); LDB8(bfrB, 0, 1); }, STG_B(1, 1, (t0 + 1) * 64 + 32), "vmcnt(4)")
    PHASE8(0, afrA, bfrB, LDA8(afrB, 0, 1, 1), ((void)0), "vmcnt(4)")
    PHASE8(1, afrB, bfrB, { LDA8(afrA, 1, 0, 0); LDB8(bfrA, 1, 0); }, ((void)0), "vmcnt(4)")
    PHASE8(0, afrA, bfrA, LDA8(afrB, 1, 0, 1), ((void)0), "vmcnt(0)")
    PHASE8(1, afrB, bfrA, { LDA8(afrA, 1, 1, 0); LDB8(bfrB, 1, 1); }, ((void)0), "vmcnt(0)")
    PHASE8(0, afrA, bfrB, LDA8(afrB, 1, 1, 1), ((void)0), "vmcnt(0)")
    PHASE8(1, afrB, bfrB, ((void)0), ((void)0), "vmcnt(0)")
  }
#undef PHASE8
#undef LDA8
#undef LDB8
#undef STG_A
#undef STG_B

  EPILOGUE(MODE, 8)
}

// ---------------- causal flash attention: fixed-max softmax + ones-MFMA row sums ------
__global__ __launch_bounds__(512) void attn_kernel(const u16* __restrict__ Q,
                                                   const u16* __restrict__ Kg,
                                                   const u16* __restrict__ Vt,
                                                   u16* __restrict__ ctx) {
  __shared__ u16 lK[2][64 * 64];
  __shared__ u16 lV[2][64 * 64];
  __shared__ u16 Plds[8][16 * 64];
  const int tid = threadIdx.x;
  const int w = tid >> 6, lane = tid & 63;
  const int lo = lane & 15, hi = lane >> 4;
  const int bh = blockIdx.x;
  const int j = blockIdx.y;
  const u16* Qb = Q + (size_t)bh * 2048 * 64;
  const u16* Kb = Kg + (size_t)bh * 2048 * 64;
  const u16* Vb = Vt + (size_t)bh * 64 * 2048;
  u16* Pw = Plds[w];
  const int nt0 = 2 * j + 2;

  const int rowS = tid >> 3;
  const int ugS = (tid & 7) ^ (rowS & 7);

#define STAGE(BUF, KB)                                                         \
  do {                                                                         \
    gload_lds16(Kb + (size_t)((KB) + rowS) * 64 + ugS * 8, &lK[BUF][tid * 8]); \
    gload_lds16(Vb + (size_t)rowS * 2048 + (KB) + ugS * 8, &lV[BUF][tid * 8]); \
  } while (0)

  const int b = bh >> 4, h = bh & 15;
  const float SCALE = 0.18033688011112042f;  // 0.125 * log2(e)

  bf16x8 ones;
#pragma unroll
  for (int i = 0; i < 8; ++i) ones[i] = (short)0x3F80;  // bf16 1.0

  int qt = j;
  int qw = qt * 128 + w * 16;

  bf16x8 qf[2];
#pragma unroll
  for (int kc = 0; kc < 2; ++kc)
    qf[kc] = *(const bf16x8*)&Qb[(size_t)(qw + lo) * 64 + kc * 32 + hi * 8];

  fx4 accO[4];
  fx4 accS = (fx4){0.f, 0.f, 0.f, 0.f};
#pragma unroll
  for (int t2 = 0; t2 < 4; ++t2) accO[t2] = (fx4){0.f, 0.f, 0.f, 0.f};

  STAGE(0, 0);
  __syncthreads();

  int buf = 0;
  for (int t = 0; t < 34; ++t) {
    if (t + 1 < 34) {
      const int tn = t + 1;
      const int kbn = (tn < nt0 ? tn : tn - nt0) * 64;
      STAGE(buf ^ 1, kbn);
    }
    if (t == nt0) {  // flush q-tile j, switch to 15-j
#pragma unroll
      for (int t2 = 0; t2 < 4; ++t2)
#pragma unroll
        for (int r = 0; r < 4; ++r) {
          const int rg = b * 2048 + qw + hi * 4 + r;
          const int cg = h * 64 + t2 * 16 + lo;
          ctx[(size_t)rg * 1024 + cg] = f2bf(accO[t2][r] / accS[r]);
        }
      qt = 15 - j;
      qw = qt * 128 + w * 16;
#pragma unroll
      for (int kc = 0; kc < 2; ++kc)
        qf[kc] = *(const bf16x8*)&Qb[(size_t)(qw + lo) * 64 + kc * 32 + hi * 8];
#pragma unroll
      for (int t2 = 0; t2 < 4; ++t2) accO[t2] = (fx4){0.f, 0.f, 0.f, 0.f};
      accS = (fx4){0.f, 0.f, 0.f, 0.f};
    }
    const int kb = (t < nt0 ? t : t - nt0) * 64;
    if (kb <= qw + 15) {
      const u16* lKb = lK[buf];
      const u16* lVb = lV[buf];
      fx4 s[4];
#pragma unroll
      for (int tt = 0; tt < 4; ++tt) {
        const int r = tt * 16 + lo;
        const bf16x8 kf0 = *(const bf16x8*)&lKb[r * 64 + ((hi ^ (r & 7)) << 3)];
        const bf16x8 kf1 = *(const bf16x8*)&lKb[r * 64 + (((4 + hi) ^ (r & 7)) << 3)];
        fx4 z = (fx4){0.f, 0.f, 0.f, 0.f};
        z = MFMA16(qf[0], kf0, z);
        z = MFMA16(qf[1], kf1, z);
        s[tt] = z;
      }
      if (kb + 63 > qw) {
#pragma unroll
        for (int tt = 0; tt < 4; ++tt)
#pragma unroll
          for (int r = 0; r < 4; ++r) {
            const int key = kb + tt * 16 + lo;
            const int qr = qw + hi * 4 + r;
            s[tt][r] = (key > qr) ? 0.f : exp2f(s[tt][r] * SCALE);
          }
      } else {
#pragma unroll
        for (int tt = 0; tt < 4; ++tt)
#pragma unroll
          for (int r = 0; r < 4; ++r) s[tt][r] = exp2f(s[tt][r] * SCALE);
      }
#pragma unroll
      for (int r = 0; r < 4; ++r) {
        unsigned pk01, pk23;
        asm("v_cvt_pk_bf16_f32 %0, %1, %2" : "=v"(pk01) : "v"(s[0][r]), "v"(s[1][r]));
        asm("v_cvt_pk_bf16_f32 %0, %1, %2" : "=v"(pk23) : "v"(s[2][r]), "v"(s[3][r]));
        const int row = hi * 4 + r;
        const int sw = (row & 7) << 4;
        const int rbase = row * 128;
        Pw[(rbase + (((0 * 16 + lo) * 2) ^ sw)) >> 1] = (u16)pk01;
        Pw[(rbase + (((1 * 16 + lo) * 2) ^ sw)) >> 1] = (u16)(pk01 >> 16);
        Pw[(rbase + (((2 * 16 + lo) * 2) ^ sw)) >> 1] = (u16)pk23;
        Pw[(rbase + (((3 * 16 + lo) * 2) ^ sw)) >> 1] = (u16)(pk23 >> 16);
      }
      asm volatile("s_waitcnt lgkmcnt(0)" ::: "memory");
      bf16x8 pf[2];
#pragma unroll
      for (int kc = 0; kc < 2; ++kc) {
        const int row = lo;
        const int colB = kc * 64 + hi * 16;
        pf[kc] = *(const bf16x8*)((const char*)Pw + row * 128 + (colB ^ ((row & 7) << 4)));
      }
      accS = MFMA16(pf[0], ones, accS);
      accS = MFMA16(pf[1], ones, accS);
#pragma unroll
      for (int t2 = 0; t2 < 4; ++t2) {
        const int r2 = t2 * 16 + lo;
        const bf16x8 vf0 = *(const bf16x8*)&lVb[r2 * 64 + ((hi ^ (r2 & 7)) << 3)];
        const bf16x8 vf1 = *(const bf16x8*)&lVb[r2 * 64 + (((4 + hi) ^ (r2 & 7)) << 3)];
        accO[t2] = MFMA16(pf[0], vf0, accO[t2]);
        accO[t2] = MFMA16(pf[1], vf1, accO[t2]);
      }
    }
    __syncthreads();
    buf ^= 1;
  }
#pragma unroll
  for (int t2 = 0; t2 < 4; ++t2)
#pragma unroll
    for (int r = 0; r < 4; ++r) {
      const int rg = b * 2048 + qw + hi * 4 + r;
      const int cg = h * 64 + t2 * 16 + lo;
      ctx[(size_t)rg * 1024 + cg] = f2bf(accO[t2][r] / accS[r]);
    }
#undef STAGE
}

// ---------------- host ----------------
extern "C" void kernel_launch(void* const* d_in, const int* in_sizes, int n_in,
                              void* d_out, int out_size, void* d_ws, size_t ws_size,
                              hipStream_t stream) {
  const float* X    = (const float*)d_in[0];
  const float* Wq   = (const float*)d_in[1];
  const float* Wk   = (const float*)d_in[2];
  const float* Wv   = (const float*)d_in[3];
  const float* Wo   = (const float*)d_in[4];
  const float* W1   = (const float*)d_in[5];
  const float* b1   = (const float*)d_in[6];
  const float* W2   = (const float*)d_in[7];
  const float* b2   = (const float*)d_in[8];
  const float* ln1s = (const float*)d_in[9];
  const float* ln1b = (const float*)d_in[10];
  const float* ln2s = (const float*)d_in[11];
  const float* ln2b = (const float*)d_in[12];

  const size_t SZ_WQKVT = 3072UL * 1024;
  const size_t SZ_WOT   = 1024UL * 1024;
  const size_t SZ_W1T   = 4096UL * 1024;
  const size_t SZ_W2T   = 1024UL * 4096;
  const size_t SZ_H     = 8192UL * 1024;
  const size_t SZ_QKV   = 64UL * 2048 * 64;

  u16* WqkvT = (u16*)d_ws;
  u16* WoT   = WqkvT + SZ_WQKVT;
  u16* W1T   = WoT + SZ_WOT;
  u16* W2T   = W1T + SZ_W1T;
  u16* hbuf  = W2T + SZ_W2T;
  u16* qbuf  = hbuf + SZ_H;
  u16* kbuf  = qbuf + SZ_QKV;
  u16* vbuf  = kbuf + SZ_QKV;
  u16* gbuf  = vbuf + SZ_QKV;
  u16* ctx   = hbuf;  // reuse (h dead after QKV GEMM)
  u16* h2    = qbuf;  // reuse (q/k dead after attention)

  float* out = (float*)d_out;
  dim3 blk(256);

  // weights -> bf16 transposed (single fused launch)
  WP wp;
  wp.s[0] = Wq; wp.s[1] = Wk; wp.s[2] = Wv; wp.s[3] = Wo; wp.s[4] = W1; wp.s[5] = W2;
  wp.d[0] = WqkvT;
  wp.d[1] = WqkvT + 1024 * 1024;
  wp.d[2] = WqkvT + 2 * 1024 * 1024;
  wp.d[3] = WoT;
  wp.d[4] = W1T;
  wp.d[5] = W2T;
  tcvt_all<<<12288, blk, 0, stream>>>(wp);

  // LN1
  ln_kernel<<<8192, blk, 0, stream>>>(X, ln1s, ln1b, hbuf);
  // QKV: 256x128 4-phase, NTM=32, NTN=24 -> 768 blocks, K=1024
  gemm4p<0><<<768, dim3(512), 0, stream>>>(hbuf, WqkvT, 1024, 24,
                                           nullptr, nullptr, qbuf, kbuf, vbuf);
  // attention
  attn_kernel<<<dim3(64, 8), dim3(512), 0, stream>>>(qbuf, kbuf, vbuf, ctx);
  // Wo + residual -> d_out (X1): 4-phase, NTN=8 -> 256 blocks
  gemm4p<1><<<256, dim3(512), 0, stream>>>(ctx, WoT, 1024, 8,
                                           out, X, nullptr, nullptr, nullptr);
  // LN2
  ln_kernel<<<8192, blk, 0, stream>>>(out, ln2s, ln2b, h2);
  // MLP1: gelu(h2@W1 + b1): 256x256 8-phase, NTN=16 -> 512 blocks
  gemm8p<2><<<512, dim3(512), 0, stream>>>(h2, W1T, 1024, 16,
                                           gbuf, b1, nullptr, nullptr, nullptr);
  // MLP2: d_out = X1 + g@W2 + b2: 4-phase, NTN=8 -> 256 blocks, K=4096
  gemm4p<3><<<256, dim3(512), 0, stream>>>(gbuf, W2T, 4096, 8,
                                           out, b2, nullptr, nullptr, nullptr);
}

// Round 20
// 395.385 us; speedup vs baseline: 1.0559x; 1.0559x over previous
//
#include <hip/hip_runtime.h>

typedef unsigned short u16;
typedef __attribute__((ext_vector_type(8))) short bf16x8;
typedef __attribute__((ext_vector_type(4))) float fx4;

#define MFMA16(a, b, c) __builtin_amdgcn_mfma_f32_16x16x32_bf16((a), (b), (c), 0, 0, 0)

__device__ __forceinline__ u16 f2bf(float f) {
  unsigned u = __float_as_uint(f);
  u += 0x7fffu + ((u >> 16) & 1u);
  return (u16)(u >> 16);
}

__device__ __forceinline__ void gload_lds16(const void* g, void* l) {
  __builtin_amdgcn_global_load_lds((const __attribute__((address_space(1))) void*)g,
                                   (__attribute__((address_space(3))) void*)l,
                                   16, 0, 0);
}

// ---------------- fused weight prep: 6 transposes (fp32 -> bf16, W^T) ----------------
struct WP {
  const float* s[6];
  u16* d[6];
};
__global__ __launch_bounds__(256) void tcvt_all(WP p) {
  __shared__ float t[32][33];
  const int id = blockIdx.x;
  int which, bx, by, R, C;
  if (id < 4096) {        // Wq,Wk,Wv,Wo: 1024x1024
    which = id >> 10;
    const int q = id & 1023;
    bx = q >> 5; by = q & 31; R = 1024; C = 1024;
  } else if (id < 8192) { // W1: 1024x4096 -> dst 4096x1024
    which = 4;
    const int q = id - 4096;
    bx = q & 127; by = q >> 7; R = 1024; C = 4096;
  } else {                // W2: 4096x1024 -> dst 1024x4096
    which = 5;
    const int q = id - 8192;
    bx = q & 31; by = q >> 5; R = 4096; C = 1024;
  }
  const float* src = p.s[which];
  u16* dst = p.d[which];
  const int tx = threadIdx.x & 31, ty = threadIdx.x >> 5;  // 32x8
#pragma unroll
  for (int i = 0; i < 4; ++i)
    t[ty + i * 8][tx] = src[(size_t)(by * 32 + ty + i * 8) * C + bx * 32 + tx];
  __syncthreads();
#pragma unroll
  for (int i = 0; i < 4; ++i)
    dst[(size_t)(bx * 32 + ty + i * 8) * R + by * 32 + tx] = f2bf(t[tx][ty + i * 8]);
}

// ---------------- layernorm: fp32 [rows][1024] -> bf16 ----------------
__global__ __launch_bounds__(256) void ln_kernel(const float* __restrict__ x,
                                                 const float* __restrict__ sc,
                                                 const float* __restrict__ sh,
                                                 u16* __restrict__ out) {
  const int row = blockIdx.x, tid = threadIdx.x;
  const float4 v = ((const float4*)(x + (size_t)row * 1024))[tid];
  float s = v.x + v.y + v.z + v.w;
  float ss = v.x * v.x + v.y * v.y + v.z * v.z + v.w * v.w;
#pragma unroll
  for (int d = 32; d >= 1; d >>= 1) {
    s += __shfl_xor(s, d);
    ss += __shfl_xor(ss, d);
  }
  __shared__ float rs[4], rq[4];
  const int w = tid >> 6;
  if ((tid & 63) == 0) { rs[w] = s; rq[w] = ss; }
  __syncthreads();
  s = rs[0] + rs[1] + rs[2] + rs[3];
  ss = rq[0] + rq[1] + rq[2] + rq[3];
  const float mean = s * (1.f / 1024.f);
  const float var = ss * (1.f / 1024.f) - mean * mean;
  const float rstd = rsqrtf(var + 1e-5f);
  const float4 g = ((const float4*)sc)[tid];
  const float4 b = ((const float4*)sh)[tid];
  ushort4 o;
  o.x = f2bf(g.x * (v.x - mean) * rstd + b.x);
  o.y = f2bf(g.y * (v.y - mean) * rstd + b.y);
  o.z = f2bf(g.z * (v.z - mean) * rstd + b.z);
  o.w = f2bf(g.w * (v.w - mean) * rstd + b.w);
  ((ushort4*)(out + (size_t)row * 1024))[tid] = o;
}

// XCD-aware tile mapping (NTM multiple of 8): bid%8=xcd; tM=xcd+8*(i/NTN); tN=i%NTN.
__device__ __forceinline__ void xcd_map(int bid, int NTN, int& tMi, int& tNi) {
  const int xcd = bid & 7, i = bid >> 3;
  tMi = xcd + 8 * (i / NTN);
  tNi = i % NTN;
}

// Inlined, fully-unrolled epilogue (rule #20: NO address-taken acc, NO runtime idx).
#define EPILOGUE(MODE, MRv)                                                        \
  _Pragma("unroll") for (int m = 0; m < (MRv); ++m) {                              \
    const int rgb = tM + wm * ((MRv) * 16) + m * 16 + hi * 4;                      \
    _Pragma("unroll") for (int n = 0; n < 4; ++n) {                                \
      const int cg = tN + wn * 64 + n * 16 + lo;                                   \
      _Pragma("unroll") for (int r = 0; r < 4; ++r) {                              \
        const float v = acc[m][n][r];                                              \
        const int rg = rgb + r;                                                    \
        if constexpr ((MODE) == 0) {                                               \
          const int which = cg >> 10, c = cg & 1023;                               \
          const int head = c >> 6, dhi = c & 63;                                   \
          const int b = rg >> 11, sidx = rg & 2047;                                \
          const int bh = b * 16 + head;                                            \
          const u16 bv = f2bf(v);                                                  \
          if (which == 0)      qd[((size_t)bh * 2048 + sidx) * 64 + dhi] = bv;     \
          else if (which == 1) kd[((size_t)bh * 2048 + sidx) * 64 + dhi] = bv;     \
          else                 vd[((size_t)bh * 64 + dhi) * 2048 + sidx] = bv;     \
        } else if constexpr ((MODE) == 1) {                                        \
          float* o = (float*)outp;                                                 \
          const size_t idx = (size_t)rg * 1024 + cg;                               \
          o[idx] = aux[idx] + v;                                                   \
        } else if constexpr ((MODE) == 2) {                                        \
          const float xx = v + aux[cg];                                            \
          const float t2 = xx + 0.044715f * xx * xx * xx;                          \
          const float e = __expf(1.5957691216057308f * t2);                        \
          const float th = 1.f - 2.f / (e + 1.f);                                  \
          ((u16*)outp)[(size_t)rg * 4096 + cg] = f2bf(0.5f * xx * (1.f + th));     \
        } else {                                                                   \
          float* o = (float*)outp;                                                 \
          const size_t idx = (size_t)rg * 1024 + cg;                               \
          o[idx] = o[idx] + v + aux[cg];                                           \
        }                                                                          \
      }                                                                            \
    }                                                                              \
  }

// ---------------- 4-phase pipelined bf16 GEMM (256x128, BK=64, 512 thr) --------------
// 8 waves = 4M x 2N, per-wave 64x64. Phase = one (tile, K-half): 8 ds_read_b128 +
// stage 1 half-tile (3 loads) + vmcnt(6) + barrier + lgkm + 16 MFMA + barrier.
// 4 half-slots/operand (96 KB). Prefetch distance 3 halves. Tail vmcnt 6->3->0->0.
template <int MODE>
__global__ __launch_bounds__(512, 1) void gemm4p(
    const u16* __restrict__ A, const u16* __restrict__ Bt, int K, int NTN,
    void* __restrict__ outp, const float* __restrict__ aux,
    u16* __restrict__ qd, u16* __restrict__ kd, u16* __restrict__ vd) {
  __shared__ u16 lA[2][2][256 * 32];
  __shared__ u16 lB[2][2][128 * 32];
  const int tid = threadIdx.x;
  const int lane = tid & 63, w = tid >> 6;
  const int lo = lane & 15, hi = lane >> 4;
  const int wm = w >> 1, wn = w & 1;
  int tMi, tNi;
  xcd_map(blockIdx.x, NTN, tMi, tNi);
  const int tM = tMi * 256, tN = tNi * 128;
  const int NT = K >> 6;
  const int NIT = K >> 7;

#define STG4(TI, H, GK)                                                           \
  do {                                                                            \
    _Pragma("unroll") for (int j = 0; j < 2; ++j) {                               \
      const int idx = j * 512 + tid;                                              \
      const int row = idx >> 2, u = idx & 3;                                      \
      gload_lds16(A + (size_t)(tM + row) * K + (GK) + ((u ^ ((row >> 1) & 3)) * 8), \
                  &lA[TI][H][idx * 8]);                                           \
    }                                                                             \
    {                                                                             \
      const int row = tid >> 2, u = tid & 3;                                      \
      gload_lds16(Bt + (size_t)(tN + row) * K + (GK) + ((u ^ ((row >> 1) & 3)) * 8), \
                  &lB[TI][H][tid * 8]);                                           \
    }                                                                             \
  } while (0)

#define PHASE4(TI, H, STAGE_STMT, VMSTR)                                          \
  {                                                                               \
    bf16x8 afr[4], bfr[4];                                                        \
    _Pragma("unroll") for (int mi = 0; mi < 4; ++mi) {                            \
      const int R = wm * 64 + mi * 16 + lo;                                       \
      afr[mi] = *(const bf16x8*)&lA[TI][H][R * 32 + ((hi ^ ((R >> 1) & 3)) * 8)]; \
    }                                                                             \
    _Pragma("unroll") for (int n = 0; n < 4; ++n) {                               \
      const int R = wn * 64 + n * 16 + lo;                                        \
      bfr[n] = *(const bf16x8*)&lB[TI][H][R * 32 + ((hi ^ ((R >> 1) & 3)) * 8)];  \
    }                                                                             \
    STAGE_STMT;                                                                   \
    asm volatile("s_waitcnt " VMSTR ::: "memory");                                \
    __builtin_amdgcn_s_barrier();                                                 \
    asm volatile("s_waitcnt lgkmcnt(0)" ::: "memory");                            \
    __builtin_amdgcn_sched_barrier(0);                                            \
    __builtin_amdgcn_s_setprio(1);                                                \
    _Pragma("unroll") for (int mi = 0; mi < 4; ++mi)                              \
      _Pragma("unroll") for (int n = 0; n < 4; ++n)                               \
        acc[mi][n] = MFMA16(afr[mi], bfr[n], acc[mi][n]);                         \
    __builtin_amdgcn_s_setprio(0);                                                \
    __builtin_amdgcn_sched_barrier(0);                                            \
    __builtin_amdgcn_s_barrier();                                                 \
    __builtin_amdgcn_sched_barrier(0);                                            \
  }

  fx4 acc[4][4];
#pragma unroll
  for (int m = 0; m < 4; ++m)
#pragma unroll
    for (int n = 0; n < 4; ++n) acc[m][n] = (fx4){0.f, 0.f, 0.f, 0.f};

  // prologue: halves 0,1,2 (tile0 h0/h1, tile1 h0); wait oldest (half 0) landed.
  STG4(0, 0, 0);
  STG4(0, 1, 32);
  STG4(1, 0, 64);
  asm volatile("s_waitcnt vmcnt(6)" ::: "memory");
  __builtin_amdgcn_s_barrier();
  __builtin_amdgcn_sched_barrier(0);

  for (int it = 0; it < NIT - 1; ++it) {
    const int t0 = 2 * it;
    PHASE4(0, 0, STG4(1, 1, (t0 + 1) * 64 + 32), "vmcnt(6)")
    PHASE4(0, 1, STG4(0, 0, (t0 + 2) * 64), "vmcnt(6)")
    PHASE4(1, 0, STG4(0, 1, (t0 + 2) * 64 + 32), "vmcnt(6)")
    PHASE4(1, 1, STG4(1, 0, (t0 + 3) * 64), "vmcnt(6)")
  }
  {  // final iteration: t0 = NT-2; tail vmcnts actually await last halves
    const int t0 = NT - 2;
    PHASE4(0, 0, STG4(1, 1, (t0 + 1) * 64 + 32), "vmcnt(6)")
    PHASE4(0, 1, ((void)0), "vmcnt(3)")
    PHASE4(1, 0, ((void)0), "vmcnt(0)")
    PHASE4(1, 1, ((void)0), "vmcnt(0)")
  }
#undef PHASE4
#undef STG4

  EPILOGUE(MODE, 4)
}

// ---------------- 8-phase pipelined bf16 GEMM (256x256, BK=64) — MLP1 ----------------
template <int MODE>
__global__ __launch_bounds__(512, 1) void gemm8p(
    const u16* __restrict__ A, const u16* __restrict__ Bt, int K, int NTN,
    void* __restrict__ outp, const float* __restrict__ aux,
    u16* __restrict__ qd, u16* __restrict__ kd, u16* __restrict__ vd) {
  constexpr int MR = 8, MR2 = 4;
  __shared__ u16 lA[2][2][256 * 32];
  __shared__ u16 lB[2][2][256 * 32];
  const int tid = threadIdx.x;
  const int lane = tid & 63, w = tid >> 6;
  const int lo = lane & 15, hi = lane >> 4;
  const int wm = w >> 2, wn = w & 3;
  int tMi, tNi;
  xcd_map(blockIdx.x, NTN, tMi, tNi);
  const int tM = tMi * 256, tN = tNi * 256;
  const int NT = K >> 6;
  const int NIT = K >> 7;

#define STG_A(TI, KSH, GK)                                                        \
  do {                                                                            \
    _Pragma("unroll") for (int j = 0; j < 2; ++j) {                               \
      const int idx = j * 512 + tid;                                              \
      const int row = idx >> 2, u = idx & 3;                                      \
      gload_lds16(A + (size_t)(tM + row) * K + (GK) + ((u ^ ((row >> 1) & 3)) * 8), \
                  &lA[TI][KSH][idx * 8]);                                         \
    }                                                                             \
  } while (0)
#define STG_B(TI, KSH, GK)                                                        \
  do {                                                                            \
    _Pragma("unroll") for (int j = 0; j < 2; ++j) {                               \
      const int idx = j * 512 + tid;                                              \
      const int row = idx >> 2, u = idx & 3;                                      \
      gload_lds16(Bt + (size_t)(tN + row) * K + (GK) + ((u ^ ((row >> 1) & 3)) * 8), \
                  &lB[TI][KSH][idx * 8]);                                         \
    }                                                                             \
  } while (0)
#define VMW asm volatile("s_waitcnt vmcnt(4)" ::: "memory")
#define NOPS ((void)0)

#define PHASE(P, STAGE_STMT, VM)                                                  \
  {                                                                               \
    constexpr int ksg = (P) >> 1;                                                 \
    constexpr int mh = (P) & 1;                                                   \
    constexpr int ti = ksg >> 1;                                                  \
    constexpr int ksh = ksg & 1;                                                  \
    bf16x8 afr[MR2];                                                              \
    _Pragma("unroll") for (int mi = 0; mi < MR2; ++mi) {                          \
      const int R = wm * (MR * 16) + (mh * MR2 + mi) * 16 + lo;                   \
      afr[mi] =                                                                   \
          *(const bf16x8*)&lA[ti][ksh][R * 32 + ((hi ^ ((R >> 1) & 3)) * 8)];     \
    }                                                                             \
    if constexpr (mh == 0) {                                                      \
      _Pragma("unroll") for (int n = 0; n < 4; ++n) {                             \
        const int R = wn * 64 + n * 16 + lo;                                      \
        bfr[n] =                                                                  \
            *(const bf16x8*)&lB[ti][ksh][R * 32 + ((hi ^ ((R >> 1) & 3)) * 8)];   \
      }                                                                           \
    }                                                                             \
    STAGE_STMT;                                                                   \
    VM;                                                                           \
    __builtin_amdgcn_s_barrier();                                                 \
    asm volatile("s_waitcnt lgkmcnt(0)" ::: "memory");                            \
    __builtin_amdgcn_sched_barrier(0);                                            \
    __builtin_amdgcn_s_setprio(1);                                                \
    _Pragma("unroll") for (int mi = 0; mi < MR2; ++mi)                            \
      _Pragma("unroll") for (int n = 0; n < 4; ++n)                               \
        acc[mh * MR2 + mi][n] = MFMA16(afr[mi], bfr[n], acc[mh * MR2 + mi][n]);   \
    __builtin_amdgcn_s_setprio(0);                                                \
    __builtin_amdgcn_sched_barrier(0);                                            \
    __builtin_amdgcn_s_barrier();                                                 \
    __builtin_amdgcn_sched_barrier(0);                                            \
  }

  fx4 acc[MR][4];
#pragma unroll
  for (int m = 0; m < MR; ++m)
#pragma unroll
    for (int n = 0; n < 4; ++n) acc[m][n] = (fx4){0.f, 0.f, 0.f, 0.f};
  bf16x8 bfr[4];

  STG_A(0, 0, 0);
  STG_B(0, 0, 0);
  STG_A(0, 1, 32);
  STG_B(0, 1, 32);
  STG_A(1, 0, 64);
  STG_B(1, 0, 64);
  asm volatile("s_waitcnt vmcnt(4)" ::: "memory");
  __builtin_amdgcn_s_barrier();
  __builtin_amdgcn_sched_barrier(0);

  for (int it = 0; it < NIT; ++it) {
    const int t0 = 2 * it;
    const bool g2 = (t0 + 2) < NT, g3 = (t0 + 3) < NT;
    PHASE(0, STG_A(1, 1, (t0 + 1) * 64 + 32), NOPS)
    PHASE(1, STG_B(1, 1, (t0 + 1) * 64 + 32), NOPS)
    PHASE(2, if (g2) STG_A(0, 0, (t0 + 2) * 64), NOPS)
    PHASE(3, if (g2) STG_B(0, 0, (t0 + 2) * 64), VMW)
    PHASE(4, if (g2) STG_A(0, 1, (t0 + 2) * 64 + 32), NOPS)
    PHASE(5, if (g2) STG_B(0, 1, (t0 + 2) * 64 + 32), NOPS)
    PHASE(6, if (g3) STG_A(1, 0, (t0 + 3) * 64), NOPS)
    PHASE(7, if (g3) STG_B(1, 0, (t0 + 3) * 64), VMW)
  }
#undef PHASE
#undef STG_A
#undef STG_B
#undef VMW
#undef NOPS

  EPILOGUE(MODE, MR)
}

// ---------------- causal flash attention: fixed-max softmax + ones-MFMA row sums ------
__global__ __launch_bounds__(512) void attn_kernel(const u16* __restrict__ Q,
                                                   const u16* __restrict__ Kg,
                                                   const u16* __restrict__ Vt,
                                                   u16* __restrict__ ctx) {
  __shared__ u16 lK[2][64 * 64];
  __shared__ u16 lV[2][64 * 64];
  __shared__ u16 Plds[8][16 * 64];
  const int tid = threadIdx.x;
  const int w = tid >> 6, lane = tid & 63;
  const int lo = lane & 15, hi = lane >> 4;
  const int bh = blockIdx.x;
  const int j = blockIdx.y;
  const u16* Qb = Q + (size_t)bh * 2048 * 64;
  const u16* Kb = Kg + (size_t)bh * 2048 * 64;
  const u16* Vb = Vt + (size_t)bh * 64 * 2048;
  u16* Pw = Plds[w];
  const int nt0 = 2 * j + 2;

  const int rowS = tid >> 3;
  const int ugS = (tid & 7) ^ (rowS & 7);

#define STAGE(BUF, KB)                                                         \
  do {                                                                         \
    gload_lds16(Kb + (size_t)((KB) + rowS) * 64 + ugS * 8, &lK[BUF][tid * 8]); \
    gload_lds16(Vb + (size_t)rowS * 2048 + (KB) + ugS * 8, &lV[BUF][tid * 8]); \
  } while (0)

  const int b = bh >> 4, h = bh & 15;
  const float SCALE = 0.18033688011112042f;  // 0.125 * log2(e)

  bf16x8 ones;
#pragma unroll
  for (int i = 0; i < 8; ++i) ones[i] = (short)0x3F80;  // bf16 1.0

  int qt = j;
  int qw = qt * 128 + w * 16;

  bf16x8 qf[2];
#pragma unroll
  for (int kc = 0; kc < 2; ++kc)
    qf[kc] = *(const bf16x8*)&Qb[(size_t)(qw + lo) * 64 + kc * 32 + hi * 8];

  fx4 accO[4];
  fx4 accS = (fx4){0.f, 0.f, 0.f, 0.f};
#pragma unroll
  for (int t2 = 0; t2 < 4; ++t2) accO[t2] = (fx4){0.f, 0.f, 0.f, 0.f};

  STAGE(0, 0);
  __syncthreads();

  int buf = 0;
  for (int t = 0; t < 34; ++t) {
    if (t + 1 < 34) {
      const int tn = t + 1;
      const int kbn = (tn < nt0 ? tn : tn - nt0) * 64;
      STAGE(buf ^ 1, kbn);
    }
    if (t == nt0) {  // flush q-tile j, switch to 15-j
#pragma unroll
      for (int t2 = 0; t2 < 4; ++t2)
#pragma unroll
        for (int r = 0; r < 4; ++r) {
          const int rg = b * 2048 + qw + hi * 4 + r;
          const int cg = h * 64 + t2 * 16 + lo;
          ctx[(size_t)rg * 1024 + cg] = f2bf(accO[t2][r] / accS[r]);
        }
      qt = 15 - j;
      qw = qt * 128 + w * 16;
#pragma unroll
      for (int kc = 0; kc < 2; ++kc)
        qf[kc] = *(const bf16x8*)&Qb[(size_t)(qw + lo) * 64 + kc * 32 + hi * 8];
#pragma unroll
      for (int t2 = 0; t2 < 4; ++t2) accO[t2] = (fx4){0.f, 0.f, 0.f, 0.f};
      accS = (fx4){0.f, 0.f, 0.f, 0.f};
    }
    const int kb = (t < nt0 ? t : t - nt0) * 64;
    if (kb <= qw + 15) {
      const u16* lKb = lK[buf];
      const u16* lVb = lV[buf];
      fx4 s[4];
#pragma unroll
      for (int tt = 0; tt < 4; ++tt) {
        const int r = tt * 16 + lo;
        const bf16x8 kf0 = *(const bf16x8*)&lKb[r * 64 + ((hi ^ (r & 7)) << 3)];
        const bf16x8 kf1 = *(const bf16x8*)&lKb[r * 64 + (((4 + hi) ^ (r & 7)) << 3)];
        fx4 z = (fx4){0.f, 0.f, 0.f, 0.f};
        z = MFMA16(qf[0], kf0, z);
        z = MFMA16(qf[1], kf1, z);
        s[tt] = z;
      }
      if (kb + 63 > qw) {
#pragma unroll
        for (int tt = 0; tt < 4; ++tt)
#pragma unroll
          for (int r = 0; r < 4; ++r) {
            const int key = kb + tt * 16 + lo;
            const int qr = qw + hi * 4 + r;
            s[tt][r] = (key > qr) ? 0.f : exp2f(s[tt][r] * SCALE);
          }
      } else {
#pragma unroll
        for (int tt = 0; tt < 4; ++tt)
#pragma unroll
          for (int r = 0; r < 4; ++r) s[tt][r] = exp2f(s[tt][r] * SCALE);
      }
#pragma unroll
      for (int r = 0; r < 4; ++r) {
        unsigned pk01, pk23;
        asm("v_cvt_pk_bf16_f32 %0, %1, %2" : "=v"(pk01) : "v"(s[0][r]), "v"(s[1][r]));
        asm("v_cvt_pk_bf16_f32 %0, %1, %2" : "=v"(pk23) : "v"(s[2][r]), "v"(s[3][r]));
        const int row = hi * 4 + r;
        const int sw = (row & 7) << 4;
        const int rbase = row * 128;
        Pw[(rbase + (((0 * 16 + lo) * 2) ^ sw)) >> 1] = (u16)pk01;
        Pw[(rbase + (((1 * 16 + lo) * 2) ^ sw)) >> 1] = (u16)(pk01 >> 16);
        Pw[(rbase + (((2 * 16 + lo) * 2) ^ sw)) >> 1] = (u16)pk23;
        Pw[(rbase + (((3 * 16 + lo) * 2) ^ sw)) >> 1] = (u16)(pk23 >> 16);
      }
      asm volatile("s_waitcnt lgkmcnt(0)" ::: "memory");
      bf16x8 pf[2];
#pragma unroll
      for (int kc = 0; kc < 2; ++kc) {
        const int row = lo;
        const int colB = kc * 64 + hi * 16;
        pf[kc] = *(const bf16x8*)((const char*)Pw + row * 128 + (colB ^ ((row & 7) << 4)));
      }
      accS = MFMA16(pf[0], ones, accS);
      accS = MFMA16(pf[1], ones, accS);
#pragma unroll
      for (int t2 = 0; t2 < 4; ++t2) {
        const int r2 = t2 * 16 + lo;
        const bf16x8 vf0 = *(const bf16x8*)&lVb[r2 * 64 + ((hi ^ (r2 & 7)) << 3)];
        const bf16x8 vf1 = *(const bf16x8*)&lVb[r2 * 64 + (((4 + hi) ^ (r2 & 7)) << 3)];
        accO[t2] = MFMA16(pf[0], vf0, accO[t2]);
        accO[t2] = MFMA16(pf[1], vf1, accO[t2]);
      }
    }
    __syncthreads();
    buf ^= 1;
  }
#pragma unroll
  for (int t2 = 0; t2 < 4; ++t2)
#pragma unroll
    for (int r = 0; r < 4; ++r) {
      const int rg = b * 2048 + qw + hi * 4 + r;
      const int cg = h * 64 + t2 * 16 + lo;
      ctx[(size_t)rg * 1024 + cg] = f2bf(accO[t2][r] / accS[r]);
    }
#undef STAGE
}

// ---------------- host ----------------
extern "C" void kernel_launch(void* const* d_in, const int* in_sizes, int n_in,
                              void* d_out, int out_size, void* d_ws, size_t ws_size,
                              hipStream_t stream) {
  const float* X    = (const float*)d_in[0];
  const float* Wq   = (const float*)d_in[1];
  const float* Wk   = (const float*)d_in[2];
  const float* Wv   = (const float*)d_in[3];
  const float* Wo   = (const float*)d_in[4];
  const float* W1   = (const float*)d_in[5];
  const float* b1   = (const float*)d_in[6];
  const float* W2   = (const float*)d_in[7];
  const float* b2   = (const float*)d_in[8];
  const float* ln1s = (const float*)d_in[9];
  const float* ln1b = (const float*)d_in[10];
  const float* ln2s = (const float*)d_in[11];
  const float* ln2b = (const float*)d_in[12];

  const size_t SZ_WQKVT = 3072UL * 1024;
  const size_t SZ_WOT   = 1024UL * 1024;
  const size_t SZ_W1T   = 4096UL * 1024;
  const size_t SZ_W2T   = 1024UL * 4096;
  const size_t SZ_H     = 8192UL * 1024;
  const size_t SZ_QKV   = 64UL * 2048 * 64;

  u16* WqkvT = (u16*)d_ws;
  u16* WoT   = WqkvT + SZ_WQKVT;
  u16* W1T   = WoT + SZ_WOT;
  u16* W2T   = W1T + SZ_W1T;
  u16* hbuf  = W2T + SZ_W2T;
  u16* qbuf  = hbuf + SZ_H;
  u16* kbuf  = qbuf + SZ_QKV;
  u16* vbuf  = kbuf + SZ_QKV;
  u16* gbuf  = vbuf + SZ_QKV;
  u16* ctx   = hbuf;  // reuse (h dead after QKV GEMM)
  u16* h2    = qbuf;  // reuse (q/k dead after attention)

  float* out = (float*)d_out;
  dim3 blk(256);

  // weights -> bf16 transposed (single fused launch)
  WP wp;
  wp.s[0] = Wq; wp.s[1] = Wk; wp.s[2] = Wv; wp.s[3] = Wo; wp.s[4] = W1; wp.s[5] = W2;
  wp.d[0] = WqkvT;
  wp.d[1] = WqkvT + 1024 * 1024;
  wp.d[2] = WqkvT + 2 * 1024 * 1024;
  wp.d[3] = WoT;
  wp.d[4] = W1T;
  wp.d[5] = W2T;
  tcvt_all<<<12288, blk, 0, stream>>>(wp);

  // LN1
  ln_kernel<<<8192, blk, 0, stream>>>(X, ln1s, ln1b, hbuf);
  // QKV: 256x128 4-phase, NTM=32, NTN=24 -> 768 blocks, K=1024
  gemm4p<0><<<768, dim3(512), 0, stream>>>(hbuf, WqkvT, 1024, 24,
                                           nullptr, nullptr, qbuf, kbuf, vbuf);
  // attention
  attn_kernel<<<dim3(64, 8), dim3(512), 0, stream>>>(qbuf, kbuf, vbuf, ctx);
  // Wo + residual -> d_out (X1): 4-phase, NTN=8 -> 256 blocks
  gemm4p<1><<<256, dim3(512), 0, stream>>>(ctx, WoT, 1024, 8,
                                           out, X, nullptr, nullptr, nullptr);
  // LN2
  ln_kernel<<<8192, blk, 0, stream>>>(out, ln2s, ln2b, h2);
  // MLP1: gelu(h2@W1 + b1): 256x256 8-phase, NTN=16 -> 512 blocks
  gemm8p<2><<<512, dim3(512), 0, stream>>>(h2, W1T, 1024, 16,
                                           gbuf, b1, nullptr, nullptr, nullptr);
  // MLP2: d_out = X1 + g@W2 + b2: 4-phase, NTN=8 -> 256 blocks, K=4096
  gemm4p<3><<<256, dim3(512), 0, stream>>>(gbuf, W2T, 4096, 8,
                                           out, b2, nullptr, nullptr, nullptr);
}

// Round 21
// 392.195 us; speedup vs baseline: 1.0645x; 1.0081x over previous
//
#include <hip/hip_runtime.h>

typedef unsigned short u16;
typedef __attribute__((ext_vector_type(8))) short bf16x8;
typedef __attribute__((ext_vector_type(4))) float fx4;

#define MFMA16(a, b, c) __builtin_amdgcn_mfma_f32_16x16x32_bf16((a), (b), (c), 0, 0, 0)

__device__ __forceinline__ u16 f2bf(float f) {
  unsigned u = __float_as_uint(f);
  u += 0x7fffu + ((u >> 16) & 1u);
  return (u16)(u >> 16);
}

__device__ __forceinline__ void gload_lds16(const void* g, void* l) {
  __builtin_amdgcn_global_load_lds((const __attribute__((address_space(1))) void*)g,
                                   (__attribute__((address_space(3))) void*)l,
                                   16, 0, 0);
}

// ------- fused prep: 6 weight transposes (fp32->bf16 W^T) + LN1, one launch ---------
struct WP {
  const float* s[6];
  u16* d[6];
  const float* x;     // LN1 input
  const float* sc;    // ln1 scale
  const float* sh;    // ln1 shift
  u16* h;             // LN1 output
};
__global__ __launch_bounds__(256) void prep_kernel(WP p) {
  const int id = blockIdx.x;
  if (id < 12288) {  // transpose path
    __shared__ float t[32][33];
    int which, bx, by, R, C;
    if (id < 4096) {        // Wq,Wk,Wv,Wo: 1024x1024
      which = id >> 10;
      const int q = id & 1023;
      bx = q >> 5; by = q & 31; R = 1024; C = 1024;
    } else if (id < 8192) { // W1: 1024x4096 -> dst 4096x1024
      which = 4;
      const int q = id - 4096;
      bx = q & 127; by = q >> 7; R = 1024; C = 4096;
    } else {                // W2: 4096x1024 -> dst 1024x4096
      which = 5;
      const int q = id - 8192;
      bx = q & 31; by = q >> 5; R = 4096; C = 1024;
    }
    const float* src = p.s[which];
    u16* dst = p.d[which];
    const int tx = threadIdx.x & 31, ty = threadIdx.x >> 5;  // 32x8
#pragma unroll
    for (int i = 0; i < 4; ++i)
      t[ty + i * 8][tx] = src[(size_t)(by * 32 + ty + i * 8) * C + bx * 32 + tx];
    __syncthreads();
#pragma unroll
    for (int i = 0; i < 4; ++i)
      dst[(size_t)(bx * 32 + ty + i * 8) * R + by * 32 + tx] = f2bf(t[tx][ty + i * 8]);
  } else {  // LN1 path: row = id - 12288
    const int row = id - 12288, tid = threadIdx.x;
    const float4 v = ((const float4*)(p.x + (size_t)row * 1024))[tid];
    float s = v.x + v.y + v.z + v.w;
    float ss = v.x * v.x + v.y * v.y + v.z * v.z + v.w * v.w;
#pragma unroll
    for (int d = 32; d >= 1; d >>= 1) {
      s += __shfl_xor(s, d);
      ss += __shfl_xor(ss, d);
    }
    __shared__ float rs[4], rq[4];
    const int w = tid >> 6;
    if ((tid & 63) == 0) { rs[w] = s; rq[w] = ss; }
    __syncthreads();
    s = rs[0] + rs[1] + rs[2] + rs[3];
    ss = rq[0] + rq[1] + rq[2] + rq[3];
    const float mean = s * (1.f / 1024.f);
    const float var = ss * (1.f / 1024.f) - mean * mean;
    const float rstd = rsqrtf(var + 1e-5f);
    const float4 g = ((const float4*)p.sc)[tid];
    const float4 b = ((const float4*)p.sh)[tid];
    ushort4 o;
    o.x = f2bf(g.x * (v.x - mean) * rstd + b.x);
    o.y = f2bf(g.y * (v.y - mean) * rstd + b.y);
    o.z = f2bf(g.z * (v.z - mean) * rstd + b.z);
    o.w = f2bf(g.w * (v.w - mean) * rstd + b.w);
    ((ushort4*)(p.h + (size_t)row * 1024))[tid] = o;
  }
}

// ---------------- layernorm: fp32 [rows][1024] -> bf16 (LN2) ----------------
__global__ __launch_bounds__(256) void ln_kernel(const float* __restrict__ x,
                                                 const float* __restrict__ sc,
                                                 const float* __restrict__ sh,
                                                 u16* __restrict__ out) {
  const int row = blockIdx.x, tid = threadIdx.x;
  const float4 v = ((const float4*)(x + (size_t)row * 1024))[tid];
  float s = v.x + v.y + v.z + v.w;
  float ss = v.x * v.x + v.y * v.y + v.z * v.z + v.w * v.w;
#pragma unroll
  for (int d = 32; d >= 1; d >>= 1) {
    s += __shfl_xor(s, d);
    ss += __shfl_xor(ss, d);
  }
  __shared__ float rs[4], rq[4];
  const int w = tid >> 6;
  if ((tid & 63) == 0) { rs[w] = s; rq[w] = ss; }
  __syncthreads();
  s = rs[0] + rs[1] + rs[2] + rs[3];
  ss = rq[0] + rq[1] + rq[2] + rq[3];
  const float mean = s * (1.f / 1024.f);
  const float var = ss * (1.f / 1024.f) - mean * mean;
  const float rstd = rsqrtf(var + 1e-5f);
  const float4 g = ((const float4*)sc)[tid];
  const float4 b = ((const float4*)sh)[tid];
  ushort4 o;
  o.x = f2bf(g.x * (v.x - mean) * rstd + b.x);
  o.y = f2bf(g.y * (v.y - mean) * rstd + b.y);
  o.z = f2bf(g.z * (v.z - mean) * rstd + b.z);
  o.w = f2bf(g.w * (v.w - mean) * rstd + b.w);
  ((ushort4*)(out + (size_t)row * 1024))[tid] = o;
}

// XCD-aware tile mapping (NTM multiple of 8): bid%8=xcd; tM=xcd+8*(i/NTN); tN=i%NTN.
__device__ __forceinline__ void xcd_map(int bid, int NTN, int& tMi, int& tNi) {
  const int xcd = bid & 7, i = bid >> 3;
  tMi = xcd + 8 * (i / NTN);
  tNi = i % NTN;
}

// Inlined, fully-unrolled epilogue (rule #20: NO address-taken acc, NO runtime idx).
#define EPILOGUE(MODE, MRv)                                                        \
  _Pragma("unroll") for (int m = 0; m < (MRv); ++m) {                              \
    const int rgb = tM + wm * ((MRv) * 16) + m * 16 + hi * 4;                      \
    _Pragma("unroll") for (int n = 0; n < 4; ++n) {                                \
      const int cg = tN + wn * 64 + n * 16 + lo;                                   \
      _Pragma("unroll") for (int r = 0; r < 4; ++r) {                              \
        const float v = acc[m][n][r];                                              \
        const int rg = rgb + r;                                                    \
        if constexpr ((MODE) == 0) {                                               \
          const int which = cg >> 10, c = cg & 1023;                               \
          const int head = c >> 6, dhi = c & 63;                                   \
          const int b = rg >> 11, sidx = rg & 2047;                                \
          const int bh = b * 16 + head;                                            \
          const u16 bv = f2bf(v);                                                  \
          if (which == 0)      qd[((size_t)bh * 2048 + sidx) * 64 + dhi] = bv;     \
          else if (which == 1) kd[((size_t)bh * 2048 + sidx) * 64 + dhi] = bv;     \
          else                 vd[((size_t)bh * 64 + dhi) * 2048 + sidx] = bv;     \
        } else if constexpr ((MODE) == 1) {                                        \
          float* o = (float*)outp;                                                 \
          const size_t idx = (size_t)rg * 1024 + cg;                               \
          o[idx] = aux[idx] + v;                                                   \
        } else if constexpr ((MODE) == 2) {                                        \
          const float xx = v + aux[cg];                                            \
          const float t2 = xx + 0.044715f * xx * xx * xx;                          \
          const float e = __expf(1.5957691216057308f * t2);                        \
          const float th = 1.f - 2.f / (e + 1.f);                                  \
          ((u16*)outp)[(size_t)rg * 4096 + cg] = f2bf(0.5f * xx * (1.f + th));     \
        } else {                                                                   \
          float* o = (float*)outp;                                                 \
          const size_t idx = (size_t)rg * 1024 + cg;                               \
          o[idx] = o[idx] + v + aux[cg];                                           \
        }                                                                          \
      }                                                                            \
    }                                                                              \
  }

// ---------------- 4-phase pipelined bf16 GEMM (256x128, BK=64, 512 thr) --------------
// 8 waves = 4M x 2N, per-wave 64x64. Phase = one (tile, K-half): 8 ds_read_b128 +
// stage 1 half-tile (3 loads) + vmcnt(6) + barrier + lgkm + 16 MFMA + barrier.
// 4 half-slots/operand (96 KB). Prefetch distance 3 halves. Tail vmcnt 6->3->0->0.
template <int MODE>
__global__ __launch_bounds__(512, 1) void gemm4p(
    const u16* __restrict__ A, const u16* __restrict__ Bt, int K, int NTN,
    void* __restrict__ outp, const float* __restrict__ aux,
    u16* __restrict__ qd, u16* __restrict__ kd, u16* __restrict__ vd) {
  __shared__ u16 lA[2][2][256 * 32];
  __shared__ u16 lB[2][2][128 * 32];
  const int tid = threadIdx.x;
  const int lane = tid & 63, w = tid >> 6;
  const int lo = lane & 15, hi = lane >> 4;
  const int wm = w >> 1, wn = w & 1;
  int tMi, tNi;
  xcd_map(blockIdx.x, NTN, tMi, tNi);
  const int tM = tMi * 256, tN = tNi * 128;
  const int NT = K >> 6;
  const int NIT = K >> 7;

#define STG4(TI, H, GK)                                                           \
  do {                                                                            \
    _Pragma("unroll") for (int j = 0; j < 2; ++j) {                               \
      const int idx = j * 512 + tid;                                              \
      const int row = idx >> 2, u = idx & 3;                                      \
      gload_lds16(A + (size_t)(tM + row) * K + (GK) + ((u ^ ((row >> 1) & 3)) * 8), \
                  &lA[TI][H][idx * 8]);                                           \
    }                                                                             \
    {                                                                             \
      const int row = tid >> 2, u = tid & 3;                                      \
      gload_lds16(Bt + (size_t)(tN + row) * K + (GK) + ((u ^ ((row >> 1) & 3)) * 8), \
                  &lB[TI][H][tid * 8]);                                           \
    }                                                                             \
  } while (0)

#define PHASE4(TI, H, STAGE_STMT, VMSTR)                                          \
  {                                                                               \
    bf16x8 afr[4], bfr[4];                                                        \
    _Pragma("unroll") for (int mi = 0; mi < 4; ++mi) {                            \
      const int R = wm * 64 + mi * 16 + lo;                                       \
      afr[mi] = *(const bf16x8*)&lA[TI][H][R * 32 + ((hi ^ ((R >> 1) & 3)) * 8)]; \
    }                                                                             \
    _Pragma("unroll") for (int n = 0; n < 4; ++n) {                               \
      const int R = wn * 64 + n * 16 + lo;                                        \
      bfr[n] = *(const bf16x8*)&lB[TI][H][R * 32 + ((hi ^ ((R >> 1) & 3)) * 8)];  \
    }                                                                             \
    STAGE_STMT;                                                                   \
    asm volatile("s_waitcnt " VMSTR ::: "memory");                                \
    __builtin_amdgcn_s_barrier();                                                 \
    asm volatile("s_waitcnt lgkmcnt(0)" ::: "memory");                            \
    __builtin_amdgcn_sched_barrier(0);                                            \
    __builtin_amdgcn_s_setprio(1);                                                \
    _Pragma("unroll") for (int mi = 0; mi < 4; ++mi)                              \
      _Pragma("unroll") for (int n = 0; n < 4; ++n)                               \
        acc[mi][n] = MFMA16(afr[mi], bfr[n], acc[mi][n]);                         \
    __builtin_amdgcn_s_setprio(0);                                                \
    __builtin_amdgcn_sched_barrier(0);                                            \
    __builtin_amdgcn_s_barrier();                                                 \
    __builtin_amdgcn_sched_barrier(0);                                            \
  }

  fx4 acc[4][4];
#pragma unroll
  for (int m = 0; m < 4; ++m)
#pragma unroll
    for (int n = 0; n < 4; ++n) acc[m][n] = (fx4){0.f, 0.f, 0.f, 0.f};

  // prologue: halves 0,1,2 (tile0 h0/h1, tile1 h0); wait oldest (half 0) landed.
  STG4(0, 0, 0);
  STG4(0, 1, 32);
  STG4(1, 0, 64);
  asm volatile("s_waitcnt vmcnt(6)" ::: "memory");
  __builtin_amdgcn_s_barrier();
  __builtin_amdgcn_sched_barrier(0);

  for (int it = 0; it < NIT - 1; ++it) {
    const int t0 = 2 * it;
    PHASE4(0, 0, STG4(1, 1, (t0 + 1) * 64 + 32), "vmcnt(6)")
    PHASE4(0, 1, STG4(0, 0, (t0 + 2) * 64), "vmcnt(6)")
    PHASE4(1, 0, STG4(0, 1, (t0 + 2) * 64 + 32), "vmcnt(6)")
    PHASE4(1, 1, STG4(1, 0, (t0 + 3) * 64), "vmcnt(6)")
  }
  {  // final iteration: t0 = NT-2; tail vmcnts actually await last halves
    const int t0 = NT - 2;
    PHASE4(0, 0, STG4(1, 1, (t0 + 1) * 64 + 32), "vmcnt(6)")
    PHASE4(0, 1, ((void)0), "vmcnt(3)")
    PHASE4(1, 0, ((void)0), "vmcnt(0)")
    PHASE4(1, 1, ((void)0), "vmcnt(0)")
  }
#undef PHASE4
#undef STG4

  EPILOGUE(MODE, 4)
}

// ---------------- 8-phase pipelined bf16 GEMM (256x256, BK=64) — MLP1 ----------------
template <int MODE>
__global__ __launch_bounds__(512, 1) void gemm8p(
    const u16* __restrict__ A, const u16* __restrict__ Bt, int K, int NTN,
    void* __restrict__ outp, const float* __restrict__ aux,
    u16* __restrict__ qd, u16* __restrict__ kd, u16* __restrict__ vd) {
  constexpr int MR = 8, MR2 = 4;
  __shared__ u16 lA[2][2][256 * 32];
  __shared__ u16 lB[2][2][256 * 32];
  const int tid = threadIdx.x;
  const int lane = tid & 63, w = tid >> 6;
  const int lo = lane & 15, hi = lane >> 4;
  const int wm = w >> 2, wn = w & 3;
  int tMi, tNi;
  xcd_map(blockIdx.x, NTN, tMi, tNi);
  const int tM = tMi * 256, tN = tNi * 256;
  const int NT = K >> 6;
  const int NIT = K >> 7;

#define STG_A(TI, KSH, GK)                                                        \
  do {                                                                            \
    _Pragma("unroll") for (int j = 0; j < 2; ++j) {                               \
      const int idx = j * 512 + tid;                                              \
      const int row = idx >> 2, u = idx & 3;                                      \
      gload_lds16(A + (size_t)(tM + row) * K + (GK) + ((u ^ ((row >> 1) & 3)) * 8), \
                  &lA[TI][KSH][idx * 8]);                                         \
    }                                                                             \
  } while (0)
#define STG_B(TI, KSH, GK)                                                        \
  do {                                                                            \
    _Pragma("unroll") for (int j = 0; j < 2; ++j) {                               \
      const int idx = j * 512 + tid;                                              \
      const int row = idx >> 2, u = idx & 3;                                      \
      gload_lds16(Bt + (size_t)(tN + row) * K + (GK) + ((u ^ ((row >> 1) & 3)) * 8), \
                  &lB[TI][KSH][idx * 8]);                                         \
    }                                                                             \
  } while (0)
#define VMW asm volatile("s_waitcnt vmcnt(4)" ::: "memory")
#define NOPS ((void)0)

#define PHASE(P, STAGE_STMT, VM)                                                  \
  {                                                                               \
    constexpr int ksg = (P) >> 1;                                                 \
    constexpr int mh = (P) & 1;                                                   \
    constexpr int ti = ksg >> 1;                                                  \
    constexpr int ksh = ksg & 1;                                                  \
    bf16x8 afr[MR2];                                                              \
    _Pragma("unroll") for (int mi = 0; mi < MR2; ++mi) {                          \
      const int R = wm * (MR * 16) + (mh * MR2 + mi) * 16 + lo;                   \
      afr[mi] =                                                                   \
          *(const bf16x8*)&lA[ti][ksh][R * 32 + ((hi ^ ((R >> 1) & 3)) * 8)];     \
    }                                                                             \
    if constexpr (mh == 0) {                                                      \
      _Pragma("unroll") for (int n = 0; n < 4; ++n) {                             \
        const int R = wn * 64 + n * 16 + lo;                                      \
        bfr[n] =                                                                  \
            *(const bf16x8*)&lB[ti][ksh][R * 32 + ((hi ^ ((R >> 1) & 3)) * 8)];   \
      }                                                                           \
    }                                                                             \
    STAGE_STMT;                                                                   \
    VM;                                                                           \
    __builtin_amdgcn_s_barrier();                                                 \
    asm volatile("s_waitcnt lgkmcnt(0)" ::: "memory");                            \
    __builtin_amdgcn_sched_barrier(0);                                            \
    __builtin_amdgcn_s_setprio(1);                                                \
    _Pragma("unroll") for (int mi = 0; mi < MR2; ++mi)                            \
      _Pragma("unroll") for (int n = 0; n < 4; ++n)                               \
        acc[mh * MR2 + mi][n] = MFMA16(afr[mi], bfr[n], acc[mh * MR2 + mi][n]);   \
    __builtin_amdgcn_s_setprio(0);                                                \
    __builtin_amdgcn_sched_barrier(0);                                            \
    __builtin_amdgcn_s_barrier();                                                 \
    __builtin_amdgcn_sched_barrier(0);                                            \
  }

  fx4 acc[MR][4];
#pragma unroll
  for (int m = 0; m < MR; ++m)
#pragma unroll
    for (int n = 0; n < 4; ++n) acc[m][n] = (fx4){0.f, 0.f, 0.f, 0.f};
  bf16x8 bfr[4];

  STG_A(0, 0, 0);
  STG_B(0, 0, 0);
  STG_A(0, 1, 32);
  STG_B(0, 1, 32);
  STG_A(1, 0, 64);
  STG_B(1, 0, 64);
  asm volatile("s_waitcnt vmcnt(4)" ::: "memory");
  __builtin_amdgcn_s_barrier();
  __builtin_amdgcn_sched_barrier(0);

  for (int it = 0; it < NIT; ++it) {
    const int t0 = 2 * it;
    const bool g2 = (t0 + 2) < NT, g3 = (t0 + 3) < NT;
    PHASE(0, STG_A(1, 1, (t0 + 1) * 64 + 32), NOPS)
    PHASE(1, STG_B(1, 1, (t0 + 1) * 64 + 32), NOPS)
    PHASE(2, if (g2) STG_A(0, 0, (t0 + 2) * 64), NOPS)
    PHASE(3, if (g2) STG_B(0, 0, (t0 + 2) * 64), VMW)
    PHASE(4, if (g2) STG_A(0, 1, (t0 + 2) * 64 + 32), NOPS)
    PHASE(5, if (g2) STG_B(0, 1, (t0 + 2) * 64 + 32), NOPS)
    PHASE(6, if (g3) STG_A(1, 0, (t0 + 3) * 64), NOPS)
    PHASE(7, if (g3) STG_B(1, 0, (t0 + 3) * 64), VMW)
  }
#undef PHASE
#undef STG_A
#undef STG_B
#undef VMW
#undef NOPS

  EPILOGUE(MODE, MR)
}

// ---------------- causal flash attention: fixed-max softmax + ones-MFMA row sums ------
__global__ __launch_bounds__(512) void attn_kernel(const u16* __restrict__ Q,
                                                   const u16* __restrict__ Kg,
                                                   const u16* __restrict__ Vt,
                                                   u16* __restrict__ ctx) {
  __shared__ u16 lK[2][64 * 64];
  __shared__ u16 lV[2][64 * 64];
  __shared__ u16 Plds[8][16 * 64];
  const int tid = threadIdx.x;
  const int w = tid >> 6, lane = tid & 63;
  const int lo = lane & 15, hi = lane >> 4;
  const int bh = blockIdx.x;
  const int j = blockIdx.y;
  const u16* Qb = Q + (size_t)bh * 2048 * 64;
  const u16* Kb = Kg + (size_t)bh * 2048 * 64;
  const u16* Vb = Vt + (size_t)bh * 64 * 2048;
  u16* Pw = Plds[w];
  const int nt0 = 2 * j + 2;

  const int rowS = tid >> 3;
  const int ugS = (tid & 7) ^ (rowS & 7);

#define STAGE(BUF, KB)                                                         \
  do {                                                                         \
    gload_lds16(Kb + (size_t)((KB) + rowS) * 64 + ugS * 8, &lK[BUF][tid * 8]); \
    gload_lds16(Vb + (size_t)rowS * 2048 + (KB) + ugS * 8, &lV[BUF][tid * 8]); \
  } while (0)

  const int b = bh >> 4, h = bh & 15;
  const float SCALE = 0.18033688011112042f;  // 0.125 * log2(e)

  bf16x8 ones;
#pragma unroll
  for (int i = 0; i < 8; ++i) ones[i] = (short)0x3F80;  // bf16 1.0

  int qt = j;
  int qw = qt * 128 + w * 16;

  bf16x8 qf[2];
#pragma unroll
  for (int kc = 0; kc < 2; ++kc)
    qf[kc] = *(const bf16x8*)&Qb[(size_t)(qw + lo) * 64 + kc * 32 + hi * 8];

  fx4 accO[4];
  fx4 accS = (fx4){0.f, 0.f, 0.f, 0.f};
#pragma unroll
  for (int t2 = 0; t2 < 4; ++t2) accO[t2] = (fx4){0.f, 0.f, 0.f, 0.f};

  STAGE(0, 0);
  __syncthreads();

  int buf = 0;
  for (int t = 0; t < 34; ++t) {
    if (t + 1 < 34) {
      const int tn = t + 1;
      const int kbn = (tn < nt0 ? tn : tn - nt0) * 64;
      STAGE(buf ^ 1, kbn);
    }
    if (t == nt0) {  // flush q-tile j, switch to 15-j
#pragma unroll
      for (int t2 = 0; t2 < 4; ++t2)
#pragma unroll
        for (int r = 0; r < 4; ++r) {
          const int rg = b * 2048 + qw + hi * 4 + r;
          const int cg = h * 64 + t2 * 16 + lo;
          ctx[(size_t)rg * 1024 + cg] = f2bf(accO[t2][r] / accS[r]);
        }
      qt = 15 - j;
      qw = qt * 128 + w * 16;
#pragma unroll
      for (int kc = 0; kc < 2; ++kc)
        qf[kc] = *(const bf16x8*)&Qb[(size_t)(qw + lo) * 64 + kc * 32 + hi * 8];
#pragma unroll
      for (int t2 = 0; t2 < 4; ++t2) accO[t2] = (fx4){0.f, 0.f, 0.f, 0.f};
      accS = (fx4){0.f, 0.f, 0.f, 0.f};
    }
    const int kb = (t < nt0 ? t : t - nt0) * 64;
    if (kb <= qw + 15) {
      const u16* lKb = lK[buf];
      const u16* lVb = lV[buf];
      fx4 s[4];
#pragma unroll
      for (int tt = 0; tt < 4; ++tt) {
        const int r = tt * 16 + lo;
        const bf16x8 kf0 = *(const bf16x8*)&lKb[r * 64 + ((hi ^ (r & 7)) << 3)];
        const bf16x8 kf1 = *(const bf16x8*)&lKb[r * 64 + (((4 + hi) ^ (r & 7)) << 3)];
        fx4 z = (fx4){0.f, 0.f, 0.f, 0.f};
        z = MFMA16(qf[0], kf0, z);
        z = MFMA16(qf[1], kf1, z);
        s[tt] = z;
      }
      if (kb + 63 > qw) {
#pragma unroll
        for (int tt = 0; tt < 4; ++tt)
#pragma unroll
          for (int r = 0; r < 4; ++r) {
            const int key = kb + tt * 16 + lo;
            const int qr = qw + hi * 4 + r;
            s[tt][r] = (key > qr) ? 0.f : exp2f(s[tt][r] * SCALE);
          }
      } else {
#pragma unroll
        for (int tt = 0; tt < 4; ++tt)
#pragma unroll
          for (int r = 0; r < 4; ++r) s[tt][r] = exp2f(s[tt][r] * SCALE);
      }
#pragma unroll
      for (int r = 0; r < 4; ++r) {
        unsigned pk01, pk23;
        asm("v_cvt_pk_bf16_f32 %0, %1, %2" : "=v"(pk01) : "v"(s[0][r]), "v"(s[1][r]));
        asm("v_cvt_pk_bf16_f32 %0, %1, %2" : "=v"(pk23) : "v"(s[2][r]), "v"(s[3][r]));
        const int row = hi * 4 + r;
        const int sw = (row & 7) << 4;
        const int rbase = row * 128;
        Pw[(rbase + (((0 * 16 + lo) * 2) ^ sw)) >> 1] = (u16)pk01;
        Pw[(rbase + (((1 * 16 + lo) * 2) ^ sw)) >> 1] = (u16)(pk01 >> 16);
        Pw[(rbase + (((2 * 16 + lo) * 2) ^ sw)) >> 1] = (u16)pk23;
        Pw[(rbase + (((3 * 16 + lo) * 2) ^ sw)) >> 1] = (u16)(pk23 >> 16);
      }
      asm volatile("s_waitcnt lgkmcnt(0)" ::: "memory");
      bf16x8 pf[2];
#pragma unroll
      for (int kc = 0; kc < 2; ++kc) {
        const int row = lo;
        const int colB = kc * 64 + hi * 16;
        pf[kc] = *(const bf16x8*)((const char*)Pw + row * 128 + (colB ^ ((row & 7) << 4)));
      }
      accS = MFMA16(pf[0], ones, accS);
      accS = MFMA16(pf[1], ones, accS);
#pragma unroll
      for (int t2 = 0; t2 < 4; ++t2) {
        const int r2 = t2 * 16 + lo;
        const bf16x8 vf0 = *(const bf16x8*)&lVb[r2 * 64 + ((hi ^ (r2 & 7)) << 3)];
        const bf16x8 vf1 = *(const bf16x8*)&lVb[r2 * 64 + (((4 + hi) ^ (r2 & 7)) << 3)];
        accO[t2] = MFMA16(pf[0], vf0, accO[t2]);
        accO[t2] = MFMA16(pf[1], vf1, accO[t2]);
      }
    }
    __syncthreads();
    buf ^= 1;
  }
#pragma unroll
  for (int t2 = 0; t2 < 4; ++t2)
#pragma unroll
    for (int r = 0; r < 4; ++r) {
      const int rg = b * 2048 + qw + hi * 4 + r;
      const int cg = h * 64 + t2 * 16 + lo;
      ctx[(size_t)rg * 1024 + cg] = f2bf(accO[t2][r] / accS[r]);
    }
#undef STAGE
}

// ---------------- host ----------------
extern "C" void kernel_launch(void* const* d_in, const int* in_sizes, int n_in,
                              void* d_out, int out_size, void* d_ws, size_t ws_size,
                              hipStream_t stream) {
  const float* X    = (const float*)d_in[0];
  const float* Wq   = (const float*)d_in[1];
  const float* Wk   = (const float*)d_in[2];
  const float* Wv   = (const float*)d_in[3];
  const float* Wo   = (const float*)d_in[4];
  const float* W1   = (const float*)d_in[5];
  const float* b1   = (const float*)d_in[6];
  const float* W2   = (const float*)d_in[7];
  const float* b2   = (const float*)d_in[8];
  const float* ln1s = (const float*)d_in[9];
  const float* ln1b = (const float*)d_in[10];
  const float* ln2s = (const float*)d_in[11];
  const float* ln2b = (const float*)d_in[12];

  const size_t SZ_WQKVT = 3072UL * 1024;
  const size_t SZ_WOT   = 1024UL * 1024;
  const size_t SZ_W1T   = 4096UL * 1024;
  const size_t SZ_W2T   = 1024UL * 4096;
  const size_t SZ_H     = 8192UL * 1024;
  const size_t SZ_QKV   = 64UL * 2048 * 64;

  u16* WqkvT = (u16*)d_ws;
  u16* WoT   = WqkvT + SZ_WQKVT;
  u16* W1T   = WoT + SZ_WOT;
  u16* W2T   = W1T + SZ_W1T;
  u16* hbuf  = W2T + SZ_W2T;
  u16* qbuf  = hbuf + SZ_H;
  u16* kbuf  = qbuf + SZ_QKV;
  u16* vbuf  = kbuf + SZ_QKV;
  u16* gbuf  = vbuf + SZ_QKV;
  u16* ctx   = hbuf;  // reuse (h dead after QKV GEMM)
  u16* h2    = qbuf;  // reuse (q/k dead after attention)

  float* out = (float*)d_out;
  dim3 blk(256);

  // fused prep: 6 weight transposes + LN1 (independent work, one launch)
  WP wp;
  wp.s[0] = Wq; wp.s[1] = Wk; wp.s[2] = Wv; wp.s[3] = Wo; wp.s[4] = W1; wp.s[5] = W2;
  wp.d[0] = WqkvT;
  wp.d[1] = WqkvT + 1024 * 1024;
  wp.d[2] = WqkvT + 2 * 1024 * 1024;
  wp.d[3] = WoT;
  wp.d[4] = W1T;
  wp.d[5] = W2T;
  wp.x = X; wp.sc = ln1s; wp.sh = ln1b; wp.h = hbuf;
  prep_kernel<<<12288 + 8192, blk, 0, stream>>>(wp);

  // QKV: 256x128 4-phase, NTM=32, NTN=24 -> 768 blocks, K=1024
  gemm4p<0><<<768, dim3(512), 0, stream>>>(hbuf, WqkvT, 1024, 24,
                                           nullptr, nullptr, qbuf, kbuf, vbuf);
  // attention
  attn_kernel<<<dim3(64, 8), dim3(512), 0, stream>>>(qbuf, kbuf, vbuf, ctx);
  // Wo + residual -> d_out (X1): 4-phase, NTN=8 -> 256 blocks
  gemm4p<1><<<256, dim3(512), 0, stream>>>(ctx, WoT, 1024, 8,
                                           out, X, nullptr, nullptr, nullptr);
  // LN2
  ln_kernel<<<8192, blk, 0, stream>>>(out, ln2s, ln2b, h2);
  // MLP1: gelu(h2@W1 + b1): 256x256 8-phase, NTN=16 -> 512 blocks
  gemm8p<2><<<512, dim3(512), 0, stream>>>(h2, W1T, 1024, 16,
                                           gbuf, b1, nullptr, nullptr, nullptr);
  // MLP2: d_out = X1 + g@W2 + b2: 4-phase, NTN=8 -> 256 blocks, K=4096
  gemm4p<3><<<256, dim3(512), 0, stream>>>(gbuf, W2T, 4096, 8,
                                           out, b2, nullptr, nullptr, nullptr);
}